// Round 10
// baseline (74.301 us; speedup 1.0000x reference)
//
#include <hip/hip_runtime.h>
#include <hip/hip_bf16.h>

#define B_    4
#define L_    2048
#define DIN   256
#define E_    16
#define M_    768
#define ROWS  (L_ + 1)      // 2049
#define NTOK  (B_ * L_)     // 8192
#define K8    (DIN / 8)     // 32

typedef __attribute__((ext_vector_type(8))) short bf16x8;
typedef __attribute__((ext_vector_type(4))) float f32x4;

__device__ inline short f2bf(float f) {
    __hip_bfloat16 h = __float2bfloat16(f);
    return *reinterpret_cast<const short*>(&h);
}

// ---------------------------------------------------------------------------
// prep_k: ONE dispatch, 4 independent parallel sections by blockIdx.x
// (round-7 structure — no serial stages):
//   [0,16)      bucket: block e prefix-scans mask/sid -> stable bucket list,
//               counts[e], and meta[slot]={pos*M, mod*M, role*M, rowbase}.
//   [16,1552)   pack W -> bf16 Wb[(e*32+k8)*768 + n][8]
//   [1552,2576) pack emb -> bf16 embb[tok][k] (token order, bucket-free)
//   [2576,4625) tables: cls rows + MASKED token rows + attn flags
// ---------------------------------------------------------------------------
#define SB 16
#define SW ((E_ * K8 * M_) / 256)        // 1536
#define SE ((NTOK * K8) / 256)           // 1024
#define ST ((B_ * ROWS) / 4)             // 2049

__launch_bounds__(256)
__global__ void prep_k(const float* __restrict__ emb,
                       const float* __restrict__ W,
                       const float* __restrict__ cls_content,
                       const float* __restrict__ pos_tab,
                       const float* __restrict__ id_tab,
                       const float* __restrict__ mod_tab,
                       const float* __restrict__ role_tab,
                       const int* __restrict__ pos,
                       const int* __restrict__ sid,
                       const int* __restrict__ mod,
                       const int* __restrict__ role,
                       const int* __restrict__ mask,
                       int* __restrict__ counts,
                       int* __restrict__ bucket,
                       int4* __restrict__ meta,
                       short* __restrict__ Wb,
                       short* __restrict__ embb,
                       float* __restrict__ out,
                       float* __restrict__ attn) {
    int bid = blockIdx.x, tid = threadIdx.x;

    // ---- Section A: deterministic bucket + meta via block prefix-scan ----
    if (bid < SB) {
        const int e = bid;
        __shared__ int s[256];
        const int base = tid * 32;
        int lc = 0;
#pragma unroll 8
        for (int j = 0; j < 32; ++j) {
            int i = base + j;
            lc += (mask[i] != 0 && sid[i] == e) ? 1 : 0;
        }
        s[tid] = lc;
        __syncthreads();
        for (int off = 1; off < 256; off <<= 1) {
            int v = (tid >= off) ? s[tid - off] : 0;
            __syncthreads();
            s[tid] += v;
            __syncthreads();
        }
        if (tid == 255) counts[e] = s[255];
        int w = s[tid] - lc;                  // exclusive prefix
        for (int j = 0; j < 32; ++j) {
            int i = base + j;
            if (mask[i] != 0 && sid[i] == e) {
                bucket[e * NTOK + w] = i;
                int bb = i >> 11, ll = i & (L_ - 1);
                meta[e * NTOK + w] = make_int4(pos[i] * M_, mod[i] * M_,
                                               role[i] * M_,
                                               (bb * ROWS + ll + 1) * M_);
                ++w;
            }
        }
        return;
    }
    bid -= SB;

    // ---- Section B: pack W -> bf16, k-inner-8 layout ----
    if (bid < SW) {
        int u   = bid * 256 + tid;            // (e*32+k8)*768 + n
        int n   = u % M_;
        int ek8 = u / M_;
        const float* src = W + (size_t)ek8 * 8 * M_ + n;
        bf16x8 v;
#pragma unroll
        for (int j = 0; j < 8; ++j) v[j] = f2bf(src[(size_t)j * M_]);
        *reinterpret_cast<bf16x8*>(Wb + (size_t)u * 8) = v;
        return;
    }
    bid -= SW;

    // ---- Section C: pack emb -> bf16 (token order, fully coalesced) ----
    if (bid < SE) {
        int u = bid * 256 + tid;              // tok*32 + k8
        const float* src = emb + (size_t)u * 8;
        f32x4 a0 = *reinterpret_cast<const f32x4*>(src);
        f32x4 a1 = *reinterpret_cast<const f32x4*>(src + 4);
        bf16x8 v;
#pragma unroll
        for (int j = 0; j < 4; ++j) { v[j] = f2bf(a0[j]); v[4 + j] = f2bf(a1[j]); }
        *reinterpret_cast<bf16x8*>(embb + (size_t)u * 8) = v;
        return;
    }
    bid -= SE;

    // ---- Section D: tables (cls + masked rows + attn), 4 rows/block ----
    if (tid >= 192) return;
#pragma unroll
    for (int rr = 0; rr < 4; ++rr) {
        int r = bid * 4 + rr;                 // 0 .. 8195
        int b = r / ROWS;
        int p = r % ROWS;
        float4* orow = reinterpret_cast<float4*>(out + (size_t)r * M_);

        if (p == 0) {
            const float4* c4 = reinterpret_cast<const float4*>(cls_content);
            const float4* p4 = reinterpret_cast<const float4*>(pos_tab);
            const float4* i4 = reinterpret_cast<const float4*>(id_tab + (size_t)E_ * M_);
            float4 a = c4[tid], bb = p4[tid], c = i4[tid];
            orow[tid] = make_float4(a.x + bb.x + c.x, a.y + bb.y + c.y,
                                    a.z + bb.z + c.z, a.w + bb.w + c.w);
            if (tid == 0) attn[r] = 1.0f;
            continue;
        }

        int idx = b * L_ + (p - 1);
        int mk = mask[idx];
        if (tid == 0) attn[r] = (mk != 0) ? 1.0f : 0.0f;
        if (mk != 0) continue;                // proj_k writes this row

        const float4* pr = reinterpret_cast<const float4*>(pos_tab  + (size_t)pos[idx]  * M_);
        const float4* ir = reinterpret_cast<const float4*>(id_tab   + (size_t)sid[idx]  * M_);
        const float4* mr = reinterpret_cast<const float4*>(mod_tab  + (size_t)mod[idx]  * M_);
        const float4* rt = reinterpret_cast<const float4*>(role_tab + (size_t)role[idx] * M_);
        float4 a = pr[tid], bb = ir[tid], c = mr[tid], d = rt[tid];
        orow[tid] = make_float4(a.x + bb.x + c.x + d.x, a.y + bb.y + c.y + d.y,
                                a.z + bb.z + c.z + d.z, a.w + bb.w + c.w + d.w);
    }
}

// ---------------------------------------------------------------------------
// proj_k: bf16 MFMA on pre-packed operands (round-7 proven structure).
// Block = 4 waves; tile = 16 tokens x 256 m-cols (wave owns 4 n-frags).
// A: 8 preloaded dwordx4 from embb (via bucket, depth 2).
// B: contiguous Wb chunks. Epilogue: one coalesced meta(int4) -> 3
// independent table gathers (depth 2, was 3). Writes FINAL rows, no RMW.
// Grid (16,3,16): flat%8==e%8 -> expert's Wb pinned to one XCD L2.
// IDEMPOTENT: launched twice this round to measure proj time via dur delta.
// ---------------------------------------------------------------------------
__launch_bounds__(256)
__global__ void proj_k(const short* __restrict__ embb,
                       const short* __restrict__ Wb,
                       const float* __restrict__ bias,
                       const float* __restrict__ id_tab,
                       const float* __restrict__ pos_tab,
                       const float* __restrict__ mod_tab,
                       const float* __restrict__ role_tab,
                       const int* __restrict__ counts,
                       const int* __restrict__ bucket,
                       const int4* __restrict__ meta,
                       float* __restrict__ out) {
    const int e     = blockIdx.x;        // 0..15
    const int chunk = blockIdx.y;        // 0..2
    const int slot  = blockIdx.z;        // 0..15
    const int cnt   = counts[e];
    if (cnt == 0) return;
    const int ntile = (cnt + 15) >> 4;

    const int tid  = threadIdx.x;
    const int wid  = tid >> 6;
    const int lane = tid & 63;
    const int l15  = lane & 15;
    const int lg   = lane >> 4;

    const int n0   = chunk * 256 + wid * 64;
    const int base = e * NTOK;

    float bv[4], iv[4];
#pragma unroll
    for (int nt = 0; nt < 4; ++nt) {
        int col = n0 + nt * 16 + l15;
        bv[nt] = bias[e * M_ + col];
        iv[nt] = id_tab[(size_t)e * M_ + col];   // sid == e in this bucket
    }

    for (int tile = slot; tile < ntile; tile += 16) {
        const int t0 = tile * 16;
        const int tA = bucket[base + min(t0 + l15, cnt - 1)];
        const bf16x8* arow = reinterpret_cast<const bf16x8*>(embb + (size_t)tA * DIN);

        // Preload all 8 A-frags (independent, in flight together).
        bf16x8 aF[8];
#pragma unroll
        for (int ks = 0; ks < 8; ++ks) aF[ks] = arow[ks * 4 + lg];

        f32x4 acc[4];
#pragma unroll
        for (int nt = 0; nt < 4; ++nt) acc[nt] = (f32x4){0.f, 0.f, 0.f, 0.f};

#pragma unroll
        for (int ks = 0; ks < 8; ++ks) {
            const bf16x8* bp = reinterpret_cast<const bf16x8*>(
                Wb + ((size_t)(e * K8 + ks * 4 + lg) * M_ + n0) * 8);
#pragma unroll
            for (int nt = 0; nt < 4; ++nt) {
                bf16x8 bF = bp[nt * 16 + l15];
                acc[nt] = __builtin_amdgcn_mfma_f32_16x16x32_bf16(aF[ks], bF, acc[nt], 0, 0, 0);
            }
        }

        // Epilogue: meta (coalesced int4) -> independent table gathers.
#pragma unroll
        for (int r = 0; r < 4; ++r) {
            int ridx = t0 + lg * 4 + r;
            if (ridx < cnt) {
                int4 mv = meta[base + ridx];
                float* orow = out + mv.w;
                const float* pr = pos_tab  + mv.x;
                const float* mr = mod_tab  + mv.y;
                const float* rt = role_tab + mv.z;
#pragma unroll
                for (int nt = 0; nt < 4; ++nt) {
                    int col = n0 + nt * 16 + l15;
                    orow[col] = acc[nt][r] + bv[nt] + iv[nt]
                              + pr[col] + mr[col] + rt[col];
                }
            }
        }
    }
}

// ---------------------------------------------------------------------------
extern "C" void kernel_launch(void* const* d_in, const int* in_sizes, int n_in,
                              void* d_out, int out_size, void* d_ws, size_t ws_size,
                              hipStream_t stream) {
    const float* emb      = (const float*)d_in[0];
    const float* W        = (const float*)d_in[1];
    const float* bias     = (const float*)d_in[2];
    const float* cls      = (const float*)d_in[3];
    const float* pos_tab  = (const float*)d_in[4];
    const float* id_tab   = (const float*)d_in[5];
    const float* mod_tab  = (const float*)d_in[6];
    const float* role_tab = (const float*)d_in[7];
    const int*   pos      = (const int*)d_in[8];
    const int*   sid      = (const int*)d_in[9];
    const int*   mod      = (const int*)d_in[10];
    const int*   role     = (const int*)d_in[11];
    const int*   mask     = (const int*)d_in[12];

    float* out  = (float*)d_out;
    float* attn = out + (size_t)B_ * ROWS * M_;

    // ws layout (16-B aligned):
    //   counts int[16]          @ 0
    //   bucket int[16*NTOK]     @ 64        (512 KB)
    //   meta   int4[16*NTOK]    @ 524352    (2 MB)
    //   Wb     short[16*256*768]@ 2621504   (6 MB)
    //   embb   short[NTOK*256]  @ 8912960   (4 MB)
    char* wsb = (char*)d_ws;
    int*   counts = (int*)wsb;
    int*   bucket = (int*)(wsb + 64);
    int4*  meta   = (int4*)(wsb + 64 + (size_t)E_ * NTOK * 4);
    short* Wb     = (short*)(wsb + 64 + (size_t)E_ * NTOK * 4 + (size_t)E_ * NTOK * 16);
    short* embb   = Wb + (size_t)E_ * DIN * M_;

    prep_k<<<SB + SW + SE + ST, 256, 0, stream>>>(
        emb, W, cls, pos_tab, id_tab, mod_tab, role_tab,
        pos, sid, mod, role, mask,
        counts, bucket, meta, Wb, embb, out, attn);

    // Launched TWICE (idempotent): dur delta vs round 7 isolates proj time.
    proj_k<<<dim3(16, 3, 16), 256, 0, stream>>>(
        embb, Wb, bias, id_tab, pos_tab, mod_tab, role_tab,
        counts, bucket, meta, out);

    proj_k<<<dim3(16, 3, 16), 256, 0, stream>>>(
        embb, Wb, bias, id_tab, pos_tab, mod_tab, role_tab,
        counts, bucket, meta, out);
}

// Round 11
// 46.982 us; speedup vs baseline: 1.5815x; 1.5815x over previous
//
#include <hip/hip_runtime.h>
#include <hip/hip_bf16.h>

#define B_    4
#define L_    2048
#define DIN   256
#define E_    16
#define M_    768
#define ROWS  (L_ + 1)      // 2049
#define NTOK  (B_ * L_)     // 8192
#define K8    (DIN / 8)     // 32

typedef __attribute__((ext_vector_type(8))) short bf16x8;
typedef __attribute__((ext_vector_type(4))) float f32x4;

__device__ inline short f2bf(float f) {
    __hip_bfloat16 h = __float2bfloat16(f);
    return *reinterpret_cast<const short*>(&h);
}

// ---------------------------------------------------------------------------
// prep_k: ONE dispatch, 4 independent parallel sections by blockIdx.x.
//   [0,32)      bucket: ATOMIC per-token (no serial tail). Thread owns one
//               token; if unmasked: slot=atomicAdd(counts[e]), writes bucket
//               + meta[slot]={pos*M, mod*M, role*M, rowbase}. Order
//               nondeterministic, SET + all outputs deterministic.
//   [32,1568)   pack W -> bf16 Wb[(e*32+k8)*768 + n][8]
//   [1568,2592) pack emb -> bf16 embb[tok][k] (token order)
//   [2592,4641) tables: cls rows + MASKED token rows + attn flags
// counts[] zeroed by a 64-B hipMemsetAsync before this kernel.
// ---------------------------------------------------------------------------
#define SA (NTOK / 256)                  // 32
#define SW ((E_ * K8 * M_) / 256)        // 1536
#define SE ((NTOK * K8) / 256)           // 1024
#define ST ((B_ * ROWS) / 4)             // 2049

__launch_bounds__(256)
__global__ void prep_k(const float* __restrict__ emb,
                       const float* __restrict__ W,
                       const float* __restrict__ cls_content,
                       const float* __restrict__ pos_tab,
                       const float* __restrict__ id_tab,
                       const float* __restrict__ mod_tab,
                       const float* __restrict__ role_tab,
                       const int* __restrict__ pos,
                       const int* __restrict__ sid,
                       const int* __restrict__ mod,
                       const int* __restrict__ role,
                       const int* __restrict__ mask,
                       int* __restrict__ counts,
                       int* __restrict__ bucket,
                       int4* __restrict__ meta,
                       short* __restrict__ Wb,
                       short* __restrict__ embb,
                       float* __restrict__ out,
                       float* __restrict__ attn) {
    int bid = blockIdx.x, tid = threadIdx.x;

    // ---- Section A: atomic bucket + meta (fully parallel) ----
    if (bid < SA) {
        int i = bid * 256 + tid;
        if (mask[i] != 0) {
            int e = sid[i];
            int slot = atomicAdd(&counts[e], 1);    // device-scope default
            bucket[e * NTOK + slot] = i;
            int bb = i >> 11, ll = i & (L_ - 1);
            meta[e * NTOK + slot] = make_int4(pos[i] * M_, mod[i] * M_,
                                              role[i] * M_,
                                              (bb * ROWS + ll + 1) * M_);
        }
        return;
    }
    bid -= SA;

    // ---- Section B: pack W -> bf16, k-inner-8 layout ----
    if (bid < SW) {
        int u   = bid * 256 + tid;            // (e*32+k8)*768 + n
        int n   = u % M_;
        int ek8 = u / M_;
        const float* src = W + (size_t)ek8 * 8 * M_ + n;
        bf16x8 v;
#pragma unroll
        for (int j = 0; j < 8; ++j) v[j] = f2bf(src[(size_t)j * M_]);
        *reinterpret_cast<bf16x8*>(Wb + (size_t)u * 8) = v;
        return;
    }
    bid -= SW;

    // ---- Section C: pack emb -> bf16 (token order, fully coalesced) ----
    if (bid < SE) {
        int u = bid * 256 + tid;              // tok*32 + k8
        const float* src = emb + (size_t)u * 8;
        f32x4 a0 = *reinterpret_cast<const f32x4*>(src);
        f32x4 a1 = *reinterpret_cast<const f32x4*>(src + 4);
        bf16x8 v;
#pragma unroll
        for (int j = 0; j < 4; ++j) { v[j] = f2bf(a0[j]); v[4 + j] = f2bf(a1[j]); }
        *reinterpret_cast<bf16x8*>(embb + (size_t)u * 8) = v;
        return;
    }
    bid -= SE;

    // ---- Section D: tables (cls + masked rows + attn), 4 rows/block ----
    if (tid >= 192) return;
#pragma unroll
    for (int rr = 0; rr < 4; ++rr) {
        int r = bid * 4 + rr;                 // 0 .. 8195
        int b = r / ROWS;
        int p = r % ROWS;
        float4* orow = reinterpret_cast<float4*>(out + (size_t)r * M_);

        if (p == 0) {
            const float4* c4 = reinterpret_cast<const float4*>(cls_content);
            const float4* p4 = reinterpret_cast<const float4*>(pos_tab);
            const float4* i4 = reinterpret_cast<const float4*>(id_tab + (size_t)E_ * M_);
            float4 a = c4[tid], bb = p4[tid], c = i4[tid];
            orow[tid] = make_float4(a.x + bb.x + c.x, a.y + bb.y + c.y,
                                    a.z + bb.z + c.z, a.w + bb.w + c.w);
            if (tid == 0) attn[r] = 1.0f;
            continue;
        }

        int idx = b * L_ + (p - 1);
        int mk = mask[idx];
        if (tid == 0) attn[r] = (mk != 0) ? 1.0f : 0.0f;
        if (mk != 0) continue;                // proj_k writes this row

        const float4* pr = reinterpret_cast<const float4*>(pos_tab  + (size_t)pos[idx]  * M_);
        const float4* ir = reinterpret_cast<const float4*>(id_tab   + (size_t)sid[idx]  * M_);
        const float4* mr = reinterpret_cast<const float4*>(mod_tab  + (size_t)mod[idx]  * M_);
        const float4* rt = reinterpret_cast<const float4*>(role_tab + (size_t)role[idx] * M_);
        float4 a = pr[tid], bb = ir[tid], c = mr[tid], d = rt[tid];
        orow[tid] = make_float4(a.x + bb.x + c.x + d.x, a.y + bb.y + c.y + d.y,
                                a.z + bb.z + c.z + d.z, a.w + bb.w + c.w + d.w);
    }
}

// ---------------------------------------------------------------------------
// proj_k: bf16 MFMA on pre-packed operands (round-9 structure, unchanged).
// Block = 4 waves; tile = 16 tokens x 256 m-cols (wave owns 4 n-frags).
// A: 8 preloaded dwordx4 from embb (via bucket, depth 2).
// B: contiguous Wb chunks. Epilogue: one coalesced meta(int4) -> 3
// independent table gathers (depth 2). Writes FINAL rows, no RMW.
// Grid (16,3,16): flat%8==e%8 -> expert's Wb pinned to one XCD L2.
// ---------------------------------------------------------------------------
__launch_bounds__(256)
__global__ void proj_k(const short* __restrict__ embb,
                       const short* __restrict__ Wb,
                       const float* __restrict__ bias,
                       const float* __restrict__ id_tab,
                       const float* __restrict__ pos_tab,
                       const float* __restrict__ mod_tab,
                       const float* __restrict__ role_tab,
                       const int* __restrict__ counts,
                       const int* __restrict__ bucket,
                       const int4* __restrict__ meta,
                       float* __restrict__ out) {
    const int e     = blockIdx.x;        // 0..15
    const int chunk = blockIdx.y;        // 0..2
    const int slot  = blockIdx.z;        // 0..15
    const int cnt   = counts[e];
    if (cnt == 0) return;
    const int ntile = (cnt + 15) >> 4;

    const int tid  = threadIdx.x;
    const int wid  = tid >> 6;
    const int lane = tid & 63;
    const int l15  = lane & 15;
    const int lg   = lane >> 4;

    const int n0   = chunk * 256 + wid * 64;
    const int base = e * NTOK;

    float bv[4], iv[4];
#pragma unroll
    for (int nt = 0; nt < 4; ++nt) {
        int col = n0 + nt * 16 + l15;
        bv[nt] = bias[e * M_ + col];
        iv[nt] = id_tab[(size_t)e * M_ + col];   // sid == e in this bucket
    }

    for (int tile = slot; tile < ntile; tile += 16) {
        const int t0 = tile * 16;
        const int tA = bucket[base + min(t0 + l15, cnt - 1)];
        const bf16x8* arow = reinterpret_cast<const bf16x8*>(embb + (size_t)tA * DIN);

        // Preload all 8 A-frags (independent, in flight together).
        bf16x8 aF[8];
#pragma unroll
        for (int ks = 0; ks < 8; ++ks) aF[ks] = arow[ks * 4 + lg];

        f32x4 acc[4];
#pragma unroll
        for (int nt = 0; nt < 4; ++nt) acc[nt] = (f32x4){0.f, 0.f, 0.f, 0.f};

#pragma unroll
        for (int ks = 0; ks < 8; ++ks) {
            const bf16x8* bp = reinterpret_cast<const bf16x8*>(
                Wb + ((size_t)(e * K8 + ks * 4 + lg) * M_ + n0) * 8);
#pragma unroll
            for (int nt = 0; nt < 4; ++nt) {
                bf16x8 bF = bp[nt * 16 + l15];
                acc[nt] = __builtin_amdgcn_mfma_f32_16x16x32_bf16(aF[ks], bF, acc[nt], 0, 0, 0);
            }
        }

        // Epilogue: meta (coalesced int4) -> independent table gathers.
#pragma unroll
        for (int r = 0; r < 4; ++r) {
            int ridx = t0 + lg * 4 + r;
            if (ridx < cnt) {
                int4 mv = meta[base + ridx];
                float* orow = out + mv.w;
                const float* pr = pos_tab  + mv.x;
                const float* mr = mod_tab  + mv.y;
                const float* rt = role_tab + mv.z;
#pragma unroll
                for (int nt = 0; nt < 4; ++nt) {
                    int col = n0 + nt * 16 + l15;
                    orow[col] = acc[nt][r] + bv[nt] + iv[nt]
                              + pr[col] + mr[col] + rt[col];
                }
            }
        }
    }
}

// ---------------------------------------------------------------------------
extern "C" void kernel_launch(void* const* d_in, const int* in_sizes, int n_in,
                              void* d_out, int out_size, void* d_ws, size_t ws_size,
                              hipStream_t stream) {
    const float* emb      = (const float*)d_in[0];
    const float* W        = (const float*)d_in[1];
    const float* bias     = (const float*)d_in[2];
    const float* cls      = (const float*)d_in[3];
    const float* pos_tab  = (const float*)d_in[4];
    const float* id_tab   = (const float*)d_in[5];
    const float* mod_tab  = (const float*)d_in[6];
    const float* role_tab = (const float*)d_in[7];
    const int*   pos      = (const int*)d_in[8];
    const int*   sid      = (const int*)d_in[9];
    const int*   mod      = (const int*)d_in[10];
    const int*   role     = (const int*)d_in[11];
    const int*   mask     = (const int*)d_in[12];

    float* out  = (float*)d_out;
    float* attn = out + (size_t)B_ * ROWS * M_;

    // ws layout (16-B aligned):
    //   counts int[16]          @ 0
    //   bucket int[16*NTOK]     @ 64        (512 KB)
    //   meta   int4[16*NTOK]    @ 524352    (2 MB)
    //   Wb     short[16*256*768]@ 2621504   (6 MB)
    //   embb   short[NTOK*256]  @ 8912960   (4 MB)
    char* wsb = (char*)d_ws;
    int*   counts = (int*)wsb;
    int*   bucket = (int*)(wsb + 64);
    int4*  meta   = (int4*)(wsb + 64 + (size_t)E_ * NTOK * 4);
    short* Wb     = (short*)(wsb + 64 + (size_t)E_ * NTOK * 4 + (size_t)E_ * NTOK * 16);
    short* embb   = Wb + (size_t)E_ * DIN * M_;

    hipMemsetAsync(d_ws, 0, 64, stream);

    prep_k<<<SA + SW + SE + ST, 256, 0, stream>>>(
        emb, W, cls, pos_tab, id_tab, mod_tab, role_tab,
        pos, sid, mod, role, mask,
        counts, bucket, meta, Wb, embb, out, attn);

    proj_k<<<dim3(16, 3, 16), 256, 0, stream>>>(
        embb, Wb, bias, id_tab, pos_tab, mod_tab, role_tab,
        counts, bucket, meta, out);
}